// Round 8
// baseline (117.342 us; speedup 1.0000x reference)
//
#include <hip/hip_runtime.h>
#include <hip/hip_bf16.h>

#define NB 32768      // batch rows per node
#define CD 128        // input channels
#define NNODES 6
#define OUTW 1536     // 6*256 output cols
#define KW 256        // concat K per node GEMM

typedef __attribute__((ext_vector_type(8))) short short8;
typedef __attribute__((ext_vector_type(4))) short s16x4;   // NB: 'short4' is a HIP builtin
typedef __attribute__((ext_vector_type(4))) float f32x4;

// hardware f32->bf16 (RNE)
static __device__ __forceinline__ short f2bf(float f) {
    union { __bf16 b; short s; } u;
    u.b = (__bf16)f;
    return u.s;
}

static __device__ __forceinline__ short8 pack8(f32x4 a, f32x4 b) {
    short8 p;
    #pragma unroll
    for (int j = 0; j < 4; ++j) { p[j] = f2bf(a[j]); p[4 + j] = f2bf(b[j]); }
    return p;
}

static __device__ __forceinline__ s16x4 pack4(f32x4 a) {
    s16x4 p;
    #pragma unroll
    for (int j = 0; j < 4; ++j) p[j] = f2bf(a[j]);
    return p;
}

// ---- prologue: Wcat[o][k] bf16 in d_ws; k<128 -> Wl[o][k], else Wr[o][k-128]
__global__ void prep_w(const float* __restrict__ Wl, const float* __restrict__ Wr,
                       short* __restrict__ Wb) {
    const int i = (blockIdx.x * 256 + threadIdx.x) * 8;
    const int o = i >> 8;
    const int k = i & 255;
    const float* src = (k < 128) ? (Wl + o * CD + k) : (Wr + o * CD + (k - 128));
    *(short8*)(Wb + i) = pack8(*(const f32x4*)src, *(const f32x4*)(src + 4));
}

// LDS short-index, XOR swizzle (byte ^= (r&7)<<4): panel p(0..9), row r(0..15),
// k(0..127). Bijective for 8B/16B accesses (XOR flips short-idx bits 3..5,
// below-granule bits 0..2 untouched); reads 2-way max (free, m136).
// Verified R5 (absmax ok, conflicts ~nil) + hand-checked 8B case.
#define LIDX(p, r, k) ((((p) << 11) + ((r) << 7) + (k)) ^ (((r) & 7) << 3))

// Block = 512 threads (8 waves) x 16 rows x all 1536 cols.
// Waves split the NODE dim: wave = (node-group ng, col-strip).
// acc[3][4] = 48 f32; launch_bounds(512,4) caps regs at 128 -> 4 waves/SIMD,
// 2x R5's occupancy. Swapped-operand MFMA (W=A, data=B) validated R4/R5.
__global__ __launch_bounds__(512, 4)
void sage_v6(const float* __restrict__ x, const short* __restrict__ Wb,
             const float* __restrict__ bias, float* __restrict__ out) {
    __shared__ __align__(16) short A[10 * 16 * 128];   // 40 KB

    const int t = threadIdx.x;
    const size_t row0 = (size_t)blockIdx.x * 16;

    // ---------- prep: thread -> (row r = t>>5, 4-channel chunk c = t&31).
    // Wave = 2 full rows of 512B -> perfectly coalesced global loads.
    {
        const int r = t >> 5;
        const int c = t & 31;
        const float* pb = x + (row0 + r) * CD + c * 4;
        f32x4 v0 = *(const f32x4*)(pb + 0ull * (NB * CD));
        f32x4 v1 = *(const f32x4*)(pb + 1ull * (NB * CD));
        f32x4 v2 = *(const f32x4*)(pb + 2ull * (NB * CD));
        f32x4 v3 = *(const f32x4*)(pb + 3ull * (NB * CD));
        f32x4 v4 = *(const f32x4*)(pb + 4ull * (NB * CD));
        f32x4 v5 = *(const f32x4*)(pb + 5ull * (NB * CD));
        f32x4 S01 = v0 + v1, S25 = v2 + v5, S34 = v3 + v4;
        f32x4 T = S01 + S25 + S34;
        const int k = c * 4;
        *(s16x4*)&A[LIDX(0, r, k)] = pack4((T - v0) * 0.2f);      // g0
        *(s16x4*)&A[LIDX(1, r, k)] = pack4((T - v1) * 0.2f);      // g1
        *(s16x4*)&A[LIDX(2, r, k)] = pack4((S01 + S34) * 0.25f);  // g25
        *(s16x4*)&A[LIDX(3, r, k)] = pack4((S01 + S25) * 0.25f);  // g34
        *(s16x4*)&A[LIDX(4, r, k)] = pack4(v0);
        *(s16x4*)&A[LIDX(5, r, k)] = pack4(v1);
        *(s16x4*)&A[LIDX(6, r, k)] = pack4(v2);
        *(s16x4*)&A[LIDX(7, r, k)] = pack4(v3);
        *(s16x4*)&A[LIDX(8, r, k)] = pack4(v4);
        *(s16x4*)&A[LIDX(9, r, k)] = pack4(v5);
    }
    __syncthreads();

    // ---------- compute: wave wv = ng*4 + strip; ng = node group (0:{0,1,2},
    // 1:{3,4,5}), strip = 64-col strip of each node's 256 cols.
    const int lane = t & 63;
    const int wv = t >> 6;
    const int ng = wv >> 2;
    const int strip = wv & 3;
    const int lo = lane & 15;
    const int hi = lane >> 4;
    // agg panels per group: ng0 -> {g0,g1,g25} = {0,1,2}; ng1 -> {g34,g34,g25}
    const int paA = ng ? 3 : 0;
    const int paB = ng ? 3 : 1;
    const int pxb = 4 + ng * 3;

    f32x4 acc[3][4];
    #pragma unroll
    for (int n = 0; n < 3; ++n)
        #pragma unroll
        for (int i = 0; i < 4; ++i) acc[n][i] = (f32x4){0.f, 0.f, 0.f, 0.f};

    #pragma unroll
    for (int m = 0; m < 4; ++m) {
        const int kk = m * 32 + hi * 8;
        short8 fgA = *(const short8*)&A[LIDX(paA, lo, kk)];
        short8 fgB = *(const short8*)&A[LIDX(paB, lo, kk)];
        short8 fgC = *(const short8*)&A[LIDX(2,   lo, kk)];
        short8 fx0 = *(const short8*)&A[LIDX(pxb + 0, lo, kk)];
        short8 fx1 = *(const short8*)&A[LIDX(pxb + 1, lo, kk)];
        short8 fx2 = *(const short8*)&A[LIDX(pxb + 2, lo, kk)];

        #pragma unroll
        for (int i = 0; i < 4; ++i) {
            const int o = strip * 64 + i * 16 + lo;
            short8 wa = *(const short8*)&Wb[o * KW + kk];          // Wl half
            short8 wx = *(const short8*)&Wb[o * KW + 128 + kk];    // Wr half
            acc[0][i] = __builtin_amdgcn_mfma_f32_16x16x32_bf16(wa, fgA, acc[0][i], 0, 0, 0);
            acc[1][i] = __builtin_amdgcn_mfma_f32_16x16x32_bf16(wa, fgB, acc[1][i], 0, 0, 0);
            acc[2][i] = __builtin_amdgcn_mfma_f32_16x16x32_bf16(wa, fgC, acc[2][i], 0, 0, 0);
            acc[0][i] = __builtin_amdgcn_mfma_f32_16x16x32_bf16(wx, fx0, acc[0][i], 0, 0, 0);
            acc[1][i] = __builtin_amdgcn_mfma_f32_16x16x32_bf16(wx, fx1, acc[1][i], 0, 0, 0);
            acc[2][i] = __builtin_amdgcn_mfma_f32_16x16x32_bf16(wx, fx2, acc[2][i], 0, 0, 0);
        }
    }

    // ---------- epilogue: lane's f32x4 = out[row0+lo][col..col+3],
    // col = (ng*3+n)*256 + strip*64 + i*16 + hi*4 [R4/R5-validated].
    // BIAS IS PER-NODE-CHANNEL (256 elems, broadcast over nodes) -> col & 255.
    // Non-temporal stores: output write-once -> keep out of L2, W stays hot.
    #pragma unroll
    for (int n = 0; n < 3; ++n) {
        #pragma unroll
        for (int i = 0; i < 4; ++i) {
            const int ocol = strip * 64 + i * 16 + hi * 4;       // within-node channel
            const int col = (ng * 3 + n) * 256 + ocol;           // global out col
            f32x4 v = acc[n][i] + *(const f32x4*)&bias[ocol];
            f32x4 g;
            #pragma unroll
            for (int j = 0; j < 4; ++j) {
                const float s = v[j] * (0.7978845608f + 0.0356774081f * v[j] * v[j]);
                const float r = __builtin_amdgcn_exp2f(-2.885390082f * s);
                g[j] = v[j] * __builtin_amdgcn_rcpf(1.0f + r);
            }
            __builtin_nontemporal_store(g, (f32x4*)&out[(row0 + lo) * OUTW + col]);
        }
    }
}

extern "C" void kernel_launch(void* const* d_in, const int* in_sizes, int n_in,
                              void* d_out, int out_size, void* d_ws, size_t ws_size,
                              hipStream_t stream) {
    const float* x  = (const float*)d_in[0];
    const float* Wl = (const float*)d_in[1];
    const float* Wr = (const float*)d_in[2];
    const float* b  = (const float*)d_in[3];
    float* out = (float*)d_out;
    short* Wb = (short*)d_ws;   // 256*256 bf16 = 128 KB

    prep_w<<<dim3(32), dim3(256), 0, stream>>>(Wl, Wr, Wb);
    sage_v6<<<dim3(NB / 16), dim3(512), 0, stream>>>(x, Wb, b, out);
}